// Round 5
// baseline (191.410 us; speedup 1.0000x reference)
//
#include <hip/hip_runtime.h>
#include <stdint.h>

typedef int v4i __attribute__((ext_vector_type(4)));

#define EPS_F32 1.1920928955078125e-07f   // np.finfo(float32).eps = 2^-23

// ---------------------------------------------------------------------------
// Fused quant kernel: blocks [0,M) do per-token X quant, blocks [M,M+DOUT)
// do per-out-channel W quant.
// ---------------------------------------------------------------------------
__global__ __launch_bounds__(256) void quant_kernel(
    const float* __restrict__ X, const float* __restrict__ W,
    const float* __restrict__ ss,
    int8_t* __restrict__ Xq, float* __restrict__ xs,
    int8_t* __restrict__ Wq, float* __restrict__ ws,
    int DIN, int M)
{
    const int bid = blockIdx.x;
    const int tid = threadIdx.x;
    const bool isX = bid < M;
    const float* row = isX ? X + (size_t)bid * DIN
                           : W + (size_t)(bid - M) * DIN;

    float4 v[4];
    float amax = 0.f;
#pragma unroll
    for (int c = 0; c < 4; ++c) {
        const int k = c * 1024 + tid * 4;
        float4 xv = *(const float4*)(row + k);
        float4 sv = *(const float4*)(ss + k);
        float4 q;
        if (isX) { q.x = xv.x / sv.x; q.y = xv.y / sv.y;
                   q.z = xv.z / sv.z; q.w = xv.w / sv.w; }
        else     { q.x = xv.x * sv.x; q.y = xv.y * sv.y;
                   q.z = xv.z * sv.z; q.w = xv.w * sv.w; }
        v[c] = q;
        amax = fmaxf(amax, fmaxf(fmaxf(fabsf(q.x), fabsf(q.y)),
                                 fmaxf(fabsf(q.z), fabsf(q.w))));
    }
    __shared__ float red[4];
    for (int off = 32; off; off >>= 1) amax = fmaxf(amax, __shfl_xor(amax, off));
    const int lane = tid & 63, w = tid >> 6;
    if (lane == 0) red[w] = amax;
    __syncthreads();
    amax = fmaxf(fmaxf(red[0], red[1]), fmaxf(red[2], red[3]));

    float scale, lo;
    if (isX) { scale = fmaxf(amax, 1e-5f) / 127.0f;      lo = -127.f; }
    else     { scale = fmaxf(amax / 127.5f, EPS_F32);    lo = -128.f; }
    if (tid == 0) { if (isX) xs[bid] = scale; else ws[bid - M] = scale; }

    int* qout = isX ? (int*)(Xq + (size_t)bid * DIN)
                    : (int*)(Wq + (size_t)(bid - M) * DIN);
#pragma unroll
    for (int c = 0; c < 4; ++c) {
        float4 q = v[c];
        int b0 = (int)fminf(fmaxf(rintf(q.x / scale), lo), 127.f);
        int b1 = (int)fminf(fmaxf(rintf(q.y / scale), lo), 127.f);
        int b2 = (int)fminf(fmaxf(rintf(q.z / scale), lo), 127.f);
        int b3 = (int)fminf(fmaxf(rintf(q.w / scale), lo), 127.f);
        qout[c * 256 + tid] = (b0 & 255) | ((b1 & 255) << 8) |
                              ((b2 & 255) << 16) | ((b3 & 255) << 24);
    }
}

// ---------------------------------------------------------------------------
// Persistent 2-tile int8 NT GEMM, 256x256 tiles, BKB=128 bytes, 8-phase
// counted-vmcnt schedule, 8 waves, 128 KiB dbuf LDS, mfma_i32_16x16x64_i8.
// Grid = 256 (1 block/CU). Tiles (bm,bn) and (bm+4,bn) per block.
//
// vmcnt ledger (2 ops per half-tile stage):
//   steady kt:  P0-end vmcnt(4)->hB1(kt) landed; P1-end vmcnt(4)->hA1(kt);
//               P2-end barrier only; P3-end vmcnt(4)->hA0,hB0(kt+1).
//   LAST kt (pf=false; queue holds only {hB1,hA1}):  P0-end vmcnt(2)->hB1;
//               P1-end vmcnt(0)->hA1.  [Round-2..4 used vmcnt(4) = NO-OP
//               here -> unsynchronized ds_read -> replay-timing race.]
//   Loop therefore exits fully drained (vmcnt=0).
// Seg boundary: epilogue (loads+stores) -> sched_barrier -> 8 prologue
//   stages -> sched_barrier -> vmcnt(4)+barrier.  Stores are OLDER than the
//   stages, so <=4-outstanding  =>  all stores + hA0,hB0 landed; the <=4
//   remaining are {hB1,hA1} — exactly the proven initial-prologue state.
// ---------------------------------------------------------------------------
#define BM 256
#define BN 256
#define BKB 128

#define MFMA __builtin_amdgcn_mfma_i32_16x16x64_i8

__global__ __launch_bounds__(512, 2) void gemm_i8_kernel(
    const int8_t* __restrict__ Xq, const int8_t* __restrict__ Wq,
    const float* __restrict__ xs, const float* __restrict__ ws,
    const float* __restrict__ bias, float* __restrict__ Y,
    int M, int N, int K)
{
    __shared__ __align__(16) int8_t smem[131072];

    const int tid  = threadIdx.x;
    const int lane = tid & 63;
    const int w    = tid >> 6;
    const int wrow = w >> 2, wcol = w & 3;

    // 256 blocks; XCD-aware: each XCD owns an 8x8 rect of the 32x16 tile grid.
    const int bid    = blockIdx.x;
    const int xcd    = bid & 7, idx = bid >> 3;        // idx in [0,32)
    const int bmBase = (xcd >> 1) * 8 + (idx >> 3);    // seg0 bm; seg1 = +4
    const int bn     = (xcd & 1) * 8 + (idx & 7);

    const int srcSwz = ((lane & 7) ^ (lane >> 3)) << 4;  // staging source swizzle
    const int chnk0  = ((lane >> 4) ^ (lane & 7)) << 4;  // frag read, k-slice 0
    const int chnk1  = chnk0 ^ 64;                       // k-slice 1
    const int aRB = ((wrow << 6) + (lane & 15)) << 7;    // A frag row-byte base
    const int bRB = ((wcol << 5) + (lane & 15)) << 7;    // B frag row-byte base

    auto STAGE = [&](const int8_t* gtile, int region, int rowStart) {
        const int8_t* src = gtile +
            (size_t)(rowStart + (w << 3) + (lane >> 3)) * K + srcSwz;
        __builtin_amdgcn_global_load_lds(
            (const __attribute__((address_space(1))) void*)src,
            (__attribute__((address_space(3))) void*)(smem + region + ((rowStart + (w << 3)) << 7)),
            16, 0, 0);
    };

    v4i acc[8][4] = {};
    v4i aF[4][2], bF0[2][2], bF1[2][2];

    const int KT = K / BKB;   // 32

    const int8_t* bT0 = Wq + (size_t)bn * BN * K;   // same B panel both segs
    const int rowb = (lane >> 4) << 2;
    const int col  = lane & 15;

    // seg0 prologue: stage tile kt0 into buf0 in steady-state order
    {
        const int8_t* aT0 = Xq + (size_t)bmBase * BM * K;
        STAGE(aT0, 0,     0);   STAGE(aT0, 0,     64);    // hA0
        STAGE(bT0, 32768, 0);   STAGE(bT0, 32768, 64);    // hB0
        STAGE(bT0, 32768, 128); STAGE(bT0, 32768, 192);   // hB1
        STAGE(aT0, 0,     128); STAGE(aT0, 0,     192);   // hA1
        asm volatile("s_waitcnt vmcnt(4)" ::: "memory");   // hA0,hB0 landed
        __builtin_amdgcn_s_barrier();
        __builtin_amdgcn_sched_barrier(0);
    }

    for (int seg = 0; seg < 2; ++seg) {
        const int bm = bmBase + seg * 4;
        const int8_t* aT0 = Xq + (size_t)bm * BM * K;

        for (int kt = 0; kt < KT; ++kt) {
            const int Ab  = (kt & 1) * 65536;
            const int Bb  = Ab + 32768;
            const int nAb = ((kt & 1) ^ 1) * 65536;
            const int nBb = nAb + 32768;
            const bool pf = (kt + 1 < KT);
            const int8_t* aTn = aT0 + (size_t)(kt + 1) * BKB;
            const int8_t* bTn = bT0 + (size_t)(kt + 1) * BKB;

            // -------- P0: read A-lo + B-lo; stage hA0(next); MFMA (lo,lo)
#pragma unroll
            for (int i = 0; i < 4; ++i) {
                aF[i][0] = *(const v4i*)(smem + Ab + aRB + i * 2048 + chnk0);
                aF[i][1] = *(const v4i*)(smem + Ab + aRB + i * 2048 + chnk1);
            }
#pragma unroll
            for (int j = 0; j < 2; ++j) {
                bF0[j][0] = *(const v4i*)(smem + Bb + bRB + j * 2048 + chnk0);
                bF0[j][1] = *(const v4i*)(smem + Bb + bRB + j * 2048 + chnk1);
            }
            if (pf) { STAGE(aTn, nAb, 0); STAGE(aTn, nAb, 64); }
            __builtin_amdgcn_s_barrier();
            asm volatile("s_waitcnt lgkmcnt(0)" ::: "memory");
            __builtin_amdgcn_sched_barrier(0);
            __builtin_amdgcn_s_setprio(1);
#pragma unroll
            for (int i = 0; i < 4; ++i)
#pragma unroll
                for (int j = 0; j < 2; ++j) {
                    acc[i][j] = MFMA(aF[i][0], bF0[j][0], acc[i][j], 0, 0, 0);
                    acc[i][j] = MFMA(aF[i][1], bF0[j][1], acc[i][j], 0, 0, 0);
                }
            __builtin_amdgcn_s_setprio(0);
            if (pf) asm volatile("s_waitcnt vmcnt(4)" ::: "memory"); // hB1(kt)
            else    asm volatile("s_waitcnt vmcnt(2)" ::: "memory"); // hB1(kt), queue={hB1,hA1}
            __builtin_amdgcn_s_barrier();
            __builtin_amdgcn_sched_barrier(0);

            // -------- P1: read B-hi; stage hB0(next); MFMA (lo,hi)
#pragma unroll
            for (int j = 0; j < 2; ++j) {
                bF1[j][0] = *(const v4i*)(smem + Bb + bRB + 16384 + j * 2048 + chnk0);
                bF1[j][1] = *(const v4i*)(smem + Bb + bRB + 16384 + j * 2048 + chnk1);
            }
            if (pf) { STAGE(bTn, nBb, 0); STAGE(bTn, nBb, 64); }
            __builtin_amdgcn_s_barrier();
            asm volatile("s_waitcnt lgkmcnt(0)" ::: "memory");
            __builtin_amdgcn_sched_barrier(0);
            __builtin_amdgcn_s_setprio(1);
#pragma unroll
            for (int i = 0; i < 4; ++i)
#pragma unroll
                for (int j = 0; j < 2; ++j) {
                    acc[i][2 + j] = MFMA(aF[i][0], bF1[j][0], acc[i][2 + j], 0, 0, 0);
                    acc[i][2 + j] = MFMA(aF[i][1], bF1[j][1], acc[i][2 + j], 0, 0, 0);
                }
            __builtin_amdgcn_s_setprio(0);
            if (pf) asm volatile("s_waitcnt vmcnt(4)" ::: "memory"); // hA1(kt)
            else    asm volatile("s_waitcnt vmcnt(0)" ::: "memory"); // hA1(kt), queue={hA1}
            __builtin_amdgcn_s_barrier();
            __builtin_amdgcn_sched_barrier(0);

            // -------- P2: read A-hi; stage hB1(next); MFMA (hi,lo)
#pragma unroll
            for (int i = 0; i < 4; ++i) {
                aF[i][0] = *(const v4i*)(smem + Ab + aRB + 16384 + i * 2048 + chnk0);
                aF[i][1] = *(const v4i*)(smem + Ab + aRB + 16384 + i * 2048 + chnk1);
            }
            if (pf) { STAGE(bTn, nBb, 128); STAGE(bTn, nBb, 192); }
            __builtin_amdgcn_s_barrier();
            asm volatile("s_waitcnt lgkmcnt(0)" ::: "memory");
            __builtin_amdgcn_sched_barrier(0);
            __builtin_amdgcn_s_setprio(1);
#pragma unroll
            for (int i = 0; i < 4; ++i)
#pragma unroll
                for (int j = 0; j < 2; ++j) {
                    acc[4 + i][j] = MFMA(aF[i][0], bF0[j][0], acc[4 + i][j], 0, 0, 0);
                    acc[4 + i][j] = MFMA(aF[i][1], bF0[j][1], acc[4 + i][j], 0, 0, 0);
                }
            __builtin_amdgcn_s_setprio(0);
            __builtin_amdgcn_s_barrier();                     // P3 needs nothing new
            __builtin_amdgcn_sched_barrier(0);

            // -------- P3: stage hA1(next); MFMA (hi,hi)
            if (pf) { STAGE(aTn, nAb, 128); STAGE(aTn, nAb, 192); }
            __builtin_amdgcn_s_barrier();
            __builtin_amdgcn_sched_barrier(0);
            __builtin_amdgcn_s_setprio(1);
#pragma unroll
            for (int i = 0; i < 4; ++i)
#pragma unroll
                for (int j = 0; j < 2; ++j) {
                    acc[4 + i][2 + j] = MFMA(aF[i][0], bF1[j][0], acc[4 + i][2 + j], 0, 0, 0);
                    acc[4 + i][2 + j] = MFMA(aF[i][1], bF1[j][1], acc[4 + i][2 + j], 0, 0, 0);
                }
            __builtin_amdgcn_s_setprio(0);
            asm volatile("s_waitcnt vmcnt(4)" ::: "memory");  // next hA0,hB0 (no-op on last kt)
            __builtin_amdgcn_s_barrier();
            __builtin_amdgcn_sched_barrier(0);
        }

        // ----- epilogue: dequant + bias (layout col=lane&15, row=(lane>>4)*4+reg)
        {
            float wsv[4], bv[4];
#pragma unroll
            for (int j = 0; j < 4; ++j) {
                const int n = bn * BN + ((j >> 1) << 7) + (wcol << 5) + ((j & 1) << 4) + col;
                wsv[j] = ws[n];
                bv[j]  = bias[n];
            }
#pragma unroll
            for (int i = 0; i < 8; ++i) {
                const int mbase = bm * BM + ((i >> 2) << 7) + (wrow << 6) + ((i & 3) << 4) + rowb;
#pragma unroll
                for (int r = 0; r < 4; ++r) {
                    const int m = mbase + r;
                    const float xsm = xs[m];
                    float* yrow = Y + (size_t)m * N;
#pragma unroll
                    for (int j = 0; j < 4; ++j) {
                        const int n = bn * BN + ((j >> 1) << 7) + (wcol << 5) + ((j & 1) << 4) + col;
                        yrow[n] = (float)acc[i][j][r] * xsm * wsv[j] + bv[j];
                    }
                }
            }
        }

        // ----- seg boundary: zero acc, then seg1 prologue, then drain-to-4.
        if (seg == 0) {
#pragma unroll
            for (int i = 0; i < 8; ++i)
#pragma unroll
                for (int j = 0; j < 4; ++j)
                    acc[i][j] = (v4i){0, 0, 0, 0};
            __builtin_amdgcn_sched_barrier(0);   // pin: stores stay OLDER than stages
            const int8_t* aT1 = Xq + (size_t)(bmBase + 4) * BM * K;
            STAGE(aT1, 0,     0);   STAGE(aT1, 0,     64);    // hA0
            STAGE(bT0, 32768, 0);   STAGE(bT0, 32768, 64);    // hB0
            STAGE(bT0, 32768, 128); STAGE(bT0, 32768, 192);   // hB1
            STAGE(aT1, 0,     128); STAGE(aT1, 0,     192);   // hA1
            __builtin_amdgcn_sched_barrier(0);
            asm volatile("s_waitcnt vmcnt(4)" ::: "memory");  // stores+hA0,hB0 landed
            __builtin_amdgcn_s_barrier();
            __builtin_amdgcn_sched_barrier(0);
        }
    }
}

// ---------------------------------------------------------------------------
extern "C" void kernel_launch(void* const* d_in, const int* in_sizes, int n_in,
                              void* d_out, int out_size, void* d_ws, size_t ws_size,
                              hipStream_t stream) {
    const float* X    = (const float*)d_in[0];
    const float* W    = (const float*)d_in[1];
    const float* bias = (const float*)d_in[2];
    const float* ss   = (const float*)d_in[3];

    const int DIN  = in_sizes[3];              // 4096
    const int DOUT = in_sizes[2];              // 4096
    const int M    = in_sizes[0] / DIN;        // 8192

    int8_t* Xq = (int8_t*)d_ws;
    int8_t* Wq = Xq + (size_t)M * DIN;
    float*  xs = (float*)(Wq + (size_t)DOUT * DIN);
    float*  ws = xs + M;
    float*  Y  = (float*)d_out;

    quant_kernel<<<M + DOUT, 256, 0, stream>>>(X, W, ss, Xq, xs, Wq, ws, DIN, M);
    gemm_i8_kernel<<<(M / BM) * (DOUT / BN) / 2, 512, 0, stream>>>(Xq, Wq, xs, ws, bias, Y, M, DOUT, DIN);
}

// Round 6
// 189.866 us; speedup vs baseline: 1.0081x; 1.0081x over previous
//
#include <hip/hip_runtime.h>
#include <stdint.h>

typedef int v4i __attribute__((ext_vector_type(4)));

#define EPS_F32 1.1920928955078125e-07f   // np.finfo(float32).eps = 2^-23

// ---------------------------------------------------------------------------
// Fused quant kernel: blocks [0,M) do per-token X quant, blocks [M,M+DOUT)
// do per-out-channel W quant.
// ---------------------------------------------------------------------------
__global__ __launch_bounds__(256) void quant_kernel(
    const float* __restrict__ X, const float* __restrict__ W,
    const float* __restrict__ ss,
    int8_t* __restrict__ Xq, float* __restrict__ xs,
    int8_t* __restrict__ Wq, float* __restrict__ ws,
    int DIN, int M)
{
    const int bid = blockIdx.x;
    const int tid = threadIdx.x;
    const bool isX = bid < M;
    const float* row = isX ? X + (size_t)bid * DIN
                           : W + (size_t)(bid - M) * DIN;

    float4 v[4];
    float amax = 0.f;
#pragma unroll
    for (int c = 0; c < 4; ++c) {
        const int k = c * 1024 + tid * 4;
        float4 xv = *(const float4*)(row + k);
        float4 sv = *(const float4*)(ss + k);
        float4 q;
        if (isX) { q.x = xv.x / sv.x; q.y = xv.y / sv.y;
                   q.z = xv.z / sv.z; q.w = xv.w / sv.w; }
        else     { q.x = xv.x * sv.x; q.y = xv.y * sv.y;
                   q.z = xv.z * sv.z; q.w = xv.w * sv.w; }
        v[c] = q;
        amax = fmaxf(amax, fmaxf(fmaxf(fabsf(q.x), fabsf(q.y)),
                                 fmaxf(fabsf(q.z), fabsf(q.w))));
    }
    __shared__ float red[4];
    for (int off = 32; off; off >>= 1) amax = fmaxf(amax, __shfl_xor(amax, off));
    const int lane = tid & 63, w = tid >> 6;
    if (lane == 0) red[w] = amax;
    __syncthreads();
    amax = fmaxf(fmaxf(red[0], red[1]), fmaxf(red[2], red[3]));

    float scale, lo;
    if (isX) { scale = fmaxf(amax, 1e-5f) / 127.0f;      lo = -127.f; }
    else     { scale = fmaxf(amax / 127.5f, EPS_F32);    lo = -128.f; }
    if (tid == 0) { if (isX) xs[bid] = scale; else ws[bid - M] = scale; }

    int* qout = isX ? (int*)(Xq + (size_t)bid * DIN)
                    : (int*)(Wq + (size_t)(bid - M) * DIN);
#pragma unroll
    for (int c = 0; c < 4; ++c) {
        float4 q = v[c];
        int b0 = (int)fminf(fmaxf(rintf(q.x / scale), lo), 127.f);
        int b1 = (int)fminf(fmaxf(rintf(q.y / scale), lo), 127.f);
        int b2 = (int)fminf(fmaxf(rintf(q.z / scale), lo), 127.f);
        int b3 = (int)fminf(fmaxf(rintf(q.w / scale), lo), 127.f);
        qout[c * 256 + tid] = (b0 & 255) | ((b1 & 255) << 8) |
                              ((b2 & 255) << 16) | ((b3 & 255) << 24);
    }
}

// ---------------------------------------------------------------------------
// Persistent 2-tile int8 NT GEMM, 256x256 tiles, BKB=128 bytes, 8-phase
// counted-vmcnt schedule, 8 waves, 128 KiB dbuf LDS, mfma_i32_16x16x64_i8.
// Grid = 256 (1 block/CU). Tiles (bm,bn) and (bm+4,bn) per block.
//
// vmcnt ledger (2 ops per half-tile stage):
//   steady kt:  P0-end vmcnt(4)->hB1(kt) landed; P1-end vmcnt(4)->hA1(kt);
//               P2-end barrier only; P3-end vmcnt(4)->hA0,hB0(kt+1).
//   LAST kt (pf=false; queue holds only {hB1,hA1}):  P0-end vmcnt(2)->hB1;
//               P1-end vmcnt(0)->hA1.  Loop exits fully drained.
// Seg boundary: epilogue (loads+stores) -> sched_barrier -> 8 prologue
//   stages -> sched_barrier -> vmcnt(4)+barrier.
//
// ROUND 6: removed the per-phase "asm lgkmcnt(0) + sched_barrier(0)" stall
// (template needs it only for compiler-invisible inline-asm ds_reads; ours
// are plain loads). Compiler emits per-use lgkmcnt(N) so the MFMA cluster
// starts as soon as its first fragments land -> LDS drain overlaps MFMA.
// Safety: each phase's reads are consumed by that phase's MFMAs (use-waits
// drain before the closing barrier); buffer re-stage is >=2 barriers after
// last read; vmcnt ledger untouched (memory-clobber asm orders vmem ops).
// ---------------------------------------------------------------------------
#define BM 256
#define BN 256
#define BKB 128

#define MFMA __builtin_amdgcn_mfma_i32_16x16x64_i8

__global__ __launch_bounds__(512, 2) void gemm_i8_kernel(
    const int8_t* __restrict__ Xq, const int8_t* __restrict__ Wq,
    const float* __restrict__ xs, const float* __restrict__ ws,
    const float* __restrict__ bias, float* __restrict__ Y,
    int M, int N, int K)
{
    __shared__ __align__(16) int8_t smem[131072];

    const int tid  = threadIdx.x;
    const int lane = tid & 63;
    const int w    = tid >> 6;
    const int wrow = w >> 2, wcol = w & 3;

    // 256 blocks; XCD-aware: each XCD owns an 8x8 rect of the 32x16 tile grid.
    const int bid    = blockIdx.x;
    const int xcd    = bid & 7, idx = bid >> 3;        // idx in [0,32)
    const int bmBase = (xcd >> 1) * 8 + (idx >> 3);    // seg0 bm; seg1 = +4
    const int bn     = (xcd & 1) * 8 + (idx & 7);

    const int srcSwz = ((lane & 7) ^ (lane >> 3)) << 4;  // staging source swizzle
    const int chnk0  = ((lane >> 4) ^ (lane & 7)) << 4;  // frag read, k-slice 0
    const int chnk1  = chnk0 ^ 64;                       // k-slice 1
    const int aRB = ((wrow << 6) + (lane & 15)) << 7;    // A frag row-byte base
    const int bRB = ((wcol << 5) + (lane & 15)) << 7;    // B frag row-byte base

    auto STAGE = [&](const int8_t* gtile, int region, int rowStart) {
        const int8_t* src = gtile +
            (size_t)(rowStart + (w << 3) + (lane >> 3)) * K + srcSwz;
        __builtin_amdgcn_global_load_lds(
            (const __attribute__((address_space(1))) void*)src,
            (__attribute__((address_space(3))) void*)(smem + region + ((rowStart + (w << 3)) << 7)),
            16, 0, 0);
    };

    v4i acc[8][4] = {};
    v4i aF[4][2], bF0[2][2], bF1[2][2];

    const int KT = K / BKB;   // 32

    const int8_t* bT0 = Wq + (size_t)bn * BN * K;   // same B panel both segs
    const int rowb = (lane >> 4) << 2;
    const int col  = lane & 15;

    // seg0 prologue: stage tile kt0 into buf0 in steady-state order
    {
        const int8_t* aT0 = Xq + (size_t)bmBase * BM * K;
        STAGE(aT0, 0,     0);   STAGE(aT0, 0,     64);    // hA0
        STAGE(bT0, 32768, 0);   STAGE(bT0, 32768, 64);    // hB0
        STAGE(bT0, 32768, 128); STAGE(bT0, 32768, 192);   // hB1
        STAGE(aT0, 0,     128); STAGE(aT0, 0,     192);   // hA1
        asm volatile("s_waitcnt vmcnt(4)" ::: "memory");   // hA0,hB0 landed
        __builtin_amdgcn_s_barrier();
        __builtin_amdgcn_sched_barrier(0);
    }

    for (int seg = 0; seg < 2; ++seg) {
        const int bm = bmBase + seg * 4;
        const int8_t* aT0 = Xq + (size_t)bm * BM * K;

        for (int kt = 0; kt < KT; ++kt) {
            const int Ab  = (kt & 1) * 65536;
            const int Bb  = Ab + 32768;
            const int nAb = ((kt & 1) ^ 1) * 65536;
            const int nBb = nAb + 32768;
            const bool pf = (kt + 1 < KT);
            const int8_t* aTn = aT0 + (size_t)(kt + 1) * BKB;
            const int8_t* bTn = bT0 + (size_t)(kt + 1) * BKB;

            // -------- P0: read A-lo + B-lo; stage hA0(next); MFMA (lo,lo)
#pragma unroll
            for (int i = 0; i < 4; ++i) {
                aF[i][0] = *(const v4i*)(smem + Ab + aRB + i * 2048 + chnk0);
                aF[i][1] = *(const v4i*)(smem + Ab + aRB + i * 2048 + chnk1);
            }
#pragma unroll
            for (int j = 0; j < 2; ++j) {
                bF0[j][0] = *(const v4i*)(smem + Bb + bRB + j * 2048 + chnk0);
                bF0[j][1] = *(const v4i*)(smem + Bb + bRB + j * 2048 + chnk1);
            }
            if (pf) { STAGE(aTn, nAb, 0); STAGE(aTn, nAb, 64); }
            __builtin_amdgcn_s_barrier();
            __builtin_amdgcn_s_setprio(1);
#pragma unroll
            for (int i = 0; i < 4; ++i)
#pragma unroll
                for (int j = 0; j < 2; ++j) {
                    acc[i][j] = MFMA(aF[i][0], bF0[j][0], acc[i][j], 0, 0, 0);
                    acc[i][j] = MFMA(aF[i][1], bF0[j][1], acc[i][j], 0, 0, 0);
                }
            __builtin_amdgcn_s_setprio(0);
            if (pf) asm volatile("s_waitcnt vmcnt(4)" ::: "memory"); // hB1(kt)
            else    asm volatile("s_waitcnt vmcnt(2)" ::: "memory"); // hB1(kt), queue={hB1,hA1}
            __builtin_amdgcn_s_barrier();
            __builtin_amdgcn_sched_barrier(0);

            // -------- P1: read B-hi; stage hB0(next); MFMA (lo,hi)
#pragma unroll
            for (int j = 0; j < 2; ++j) {
                bF1[j][0] = *(const v4i*)(smem + Bb + bRB + 16384 + j * 2048 + chnk0);
                bF1[j][1] = *(const v4i*)(smem + Bb + bRB + 16384 + j * 2048 + chnk1);
            }
            if (pf) { STAGE(bTn, nBb, 0); STAGE(bTn, nBb, 64); }
            __builtin_amdgcn_s_barrier();
            __builtin_amdgcn_s_setprio(1);
#pragma unroll
            for (int i = 0; i < 4; ++i)
#pragma unroll
                for (int j = 0; j < 2; ++j) {
                    acc[i][2 + j] = MFMA(aF[i][0], bF1[j][0], acc[i][2 + j], 0, 0, 0);
                    acc[i][2 + j] = MFMA(aF[i][1], bF1[j][1], acc[i][2 + j], 0, 0, 0);
                }
            __builtin_amdgcn_s_setprio(0);
            if (pf) asm volatile("s_waitcnt vmcnt(4)" ::: "memory"); // hA1(kt)
            else    asm volatile("s_waitcnt vmcnt(0)" ::: "memory"); // hA1(kt), queue={hA1}
            __builtin_amdgcn_s_barrier();
            __builtin_amdgcn_sched_barrier(0);

            // -------- P2: read A-hi; stage hB1(next); MFMA (hi,lo)
#pragma unroll
            for (int i = 0; i < 4; ++i) {
                aF[i][0] = *(const v4i*)(smem + Ab + aRB + 16384 + i * 2048 + chnk0);
                aF[i][1] = *(const v4i*)(smem + Ab + aRB + 16384 + i * 2048 + chnk1);
            }
            if (pf) { STAGE(bTn, nBb, 128); STAGE(bTn, nBb, 192); }
            __builtin_amdgcn_s_barrier();
            __builtin_amdgcn_s_setprio(1);
#pragma unroll
            for (int i = 0; i < 4; ++i)
#pragma unroll
                for (int j = 0; j < 2; ++j) {
                    acc[4 + i][j] = MFMA(aF[i][0], bF0[j][0], acc[4 + i][j], 0, 0, 0);
                    acc[4 + i][j] = MFMA(aF[i][1], bF0[j][1], acc[4 + i][j], 0, 0, 0);
                }
            __builtin_amdgcn_s_setprio(0);
            __builtin_amdgcn_s_barrier();                     // P3 needs nothing new
            __builtin_amdgcn_sched_barrier(0);

            // -------- P3: stage hA1(next); MFMA (hi,hi)
            if (pf) { STAGE(aTn, nAb, 128); STAGE(aTn, nAb, 192); }
            __builtin_amdgcn_s_barrier();
            __builtin_amdgcn_s_setprio(1);
#pragma unroll
            for (int i = 0; i < 4; ++i)
#pragma unroll
                for (int j = 0; j < 2; ++j) {
                    acc[4 + i][2 + j] = MFMA(aF[i][0], bF1[j][0], acc[4 + i][2 + j], 0, 0, 0);
                    acc[4 + i][2 + j] = MFMA(aF[i][1], bF1[j][1], acc[4 + i][2 + j], 0, 0, 0);
                }
            __builtin_amdgcn_s_setprio(0);
            asm volatile("s_waitcnt vmcnt(4)" ::: "memory");  // next hA0,hB0 (no-op on last kt)
            __builtin_amdgcn_s_barrier();
            __builtin_amdgcn_sched_barrier(0);
        }

        // ----- epilogue: dequant + bias (layout col=lane&15, row=(lane>>4)*4+reg)
        {
            float wsv[4], bv[4];
#pragma unroll
            for (int j = 0; j < 4; ++j) {
                const int n = bn * BN + ((j >> 1) << 7) + (wcol << 5) + ((j & 1) << 4) + col;
                wsv[j] = ws[n];
                bv[j]  = bias[n];
            }
#pragma unroll
            for (int i = 0; i < 8; ++i) {
                const int mbase = bm * BM + ((i >> 2) << 7) + (wrow << 6) + ((i & 3) << 4) + rowb;
#pragma unroll
                for (int r = 0; r < 4; ++r) {
                    const int m = mbase + r;
                    const float xsm = xs[m];
                    float* yrow = Y + (size_t)m * N;
#pragma unroll
                    for (int j = 0; j < 4; ++j) {
                        const int n = bn * BN + ((j >> 1) << 7) + (wcol << 5) + ((j & 1) << 4) + col;
                        yrow[n] = (float)acc[i][j][r] * xsm * wsv[j] + bv[j];
                    }
                }
            }
        }

        // ----- seg boundary: zero acc, then seg1 prologue, then drain-to-4.
        if (seg == 0) {
#pragma unroll
            for (int i = 0; i < 8; ++i)
#pragma unroll
                for (int j = 0; j < 4; ++j)
                    acc[i][j] = (v4i){0, 0, 0, 0};
            __builtin_amdgcn_sched_barrier(0);   // pin: stores stay OLDER than stages
            const int8_t* aT1 = Xq + (size_t)(bmBase + 4) * BM * K;
            STAGE(aT1, 0,     0);   STAGE(aT1, 0,     64);    // hA0
            STAGE(bT0, 32768, 0);   STAGE(bT0, 32768, 64);    // hB0
            STAGE(bT0, 32768, 128); STAGE(bT0, 32768, 192);   // hB1
            STAGE(aT1, 0,     128); STAGE(aT1, 0,     192);   // hA1
            __builtin_amdgcn_sched_barrier(0);
            asm volatile("s_waitcnt vmcnt(4)" ::: "memory");  // stores+hA0,hB0 landed
            __builtin_amdgcn_s_barrier();
            __builtin_amdgcn_sched_barrier(0);
        }
    }
}

// ---------------------------------------------------------------------------
extern "C" void kernel_launch(void* const* d_in, const int* in_sizes, int n_in,
                              void* d_out, int out_size, void* d_ws, size_t ws_size,
                              hipStream_t stream) {
    const float* X    = (const float*)d_in[0];
    const float* W    = (const float*)d_in[1];
    const float* bias = (const float*)d_in[2];
    const float* ss   = (const float*)d_in[3];

    const int DIN  = in_sizes[3];              // 4096
    const int DOUT = in_sizes[2];              // 4096
    const int M    = in_sizes[0] / DIN;        // 8192

    int8_t* Xq = (int8_t*)d_ws;
    int8_t* Wq = Xq + (size_t)M * DIN;
    float*  xs = (float*)(Wq + (size_t)DOUT * DIN);
    float*  ws = xs + M;
    float*  Y  = (float*)d_out;

    quant_kernel<<<M + DOUT, 256, 0, stream>>>(X, W, ss, Xq, xs, Wq, ws, DIN, M);
    gemm_i8_kernel<<<(M / BM) * (DOUT / BN) / 2, 512, 0, stream>>>(Xq, Wq, xs, ws, bias, Y, M, DOUT, DIN);
}

// Round 7
// 179.842 us; speedup vs baseline: 1.0643x; 1.0557x over previous
//
#include <hip/hip_runtime.h>
#include <stdint.h>

typedef int v4i __attribute__((ext_vector_type(4)));

#define EPS_F32 1.1920928955078125e-07f   // np.finfo(float32).eps = 2^-23

// ---------------------------------------------------------------------------
// Fused quant kernel: blocks [0,M) do per-token X quant, blocks [M,M+DOUT)
// do per-out-channel W quant.
// ---------------------------------------------------------------------------
__global__ __launch_bounds__(256) void quant_kernel(
    const float* __restrict__ X, const float* __restrict__ W,
    const float* __restrict__ ss,
    int8_t* __restrict__ Xq, float* __restrict__ xs,
    int8_t* __restrict__ Wq, float* __restrict__ ws,
    int DIN, int M)
{
    const int bid = blockIdx.x;
    const int tid = threadIdx.x;
    const bool isX = bid < M;
    const float* row = isX ? X + (size_t)bid * DIN
                           : W + (size_t)(bid - M) * DIN;

    float4 v[4];
    float amax = 0.f;
#pragma unroll
    for (int c = 0; c < 4; ++c) {
        const int k = c * 1024 + tid * 4;
        float4 xv = *(const float4*)(row + k);
        float4 sv = *(const float4*)(ss + k);
        float4 q;
        if (isX) { q.x = xv.x / sv.x; q.y = xv.y / sv.y;
                   q.z = xv.z / sv.z; q.w = xv.w / sv.w; }
        else     { q.x = xv.x * sv.x; q.y = xv.y * sv.y;
                   q.z = xv.z * sv.z; q.w = xv.w * sv.w; }
        v[c] = q;
        amax = fmaxf(amax, fmaxf(fmaxf(fabsf(q.x), fabsf(q.y)),
                                 fmaxf(fabsf(q.z), fabsf(q.w))));
    }
    __shared__ float red[4];
    for (int off = 32; off; off >>= 1) amax = fmaxf(amax, __shfl_xor(amax, off));
    const int lane = tid & 63, w = tid >> 6;
    if (lane == 0) red[w] = amax;
    __syncthreads();
    amax = fmaxf(fmaxf(red[0], red[1]), fmaxf(red[2], red[3]));

    float scale, lo;
    if (isX) { scale = fmaxf(amax, 1e-5f) / 127.0f;      lo = -127.f; }
    else     { scale = fmaxf(amax / 127.5f, EPS_F32);    lo = -128.f; }
    if (tid == 0) { if (isX) xs[bid] = scale; else ws[bid - M] = scale; }

    int* qout = isX ? (int*)(Xq + (size_t)bid * DIN)
                    : (int*)(Wq + (size_t)(bid - M) * DIN);
#pragma unroll
    for (int c = 0; c < 4; ++c) {
        float4 q = v[c];
        int b0 = (int)fminf(fmaxf(rintf(q.x / scale), lo), 127.f);
        int b1 = (int)fminf(fmaxf(rintf(q.y / scale), lo), 127.f);
        int b2 = (int)fminf(fmaxf(rintf(q.z / scale), lo), 127.f);
        int b3 = (int)fminf(fmaxf(rintf(q.w / scale), lo), 127.f);
        qout[c * 256 + tid] = (b0 & 255) | ((b1 & 255) << 8) |
                              ((b2 & 255) << 16) | ((b3 & 255) << 24);
    }
}

// ---------------------------------------------------------------------------
// Persistent 2-tile int8 NT GEMM, 256x256 tiles, BKB=128, 8 waves (2x4),
// 128 KiB dbuf LDS, mfma_i32_16x16x64_i8.  Grid = 256 (1 block/CU).
//
// ROUND 7: fragment-level software pipeline (reads one phase AHEAD of use):
//   P0: issue bHi(kt) ds_reads [4]  + 4 stages(next tile) + MFMA(aLo,bLo)
//   P1: issue aHi(kt) ds_reads [8]  + 4 stages(next tile) + MFMA(aLo,bHi)
//   P2: MFMA(aHi,bLo); then THE per-kt sync: vmcnt(0)+s_barrier
//       (stages were all issued >=1300cy earlier -> drain ~free)
//   P3: issue aLo,bLo(kt+1) ds_reads [12] (next buffer) + MFMA(aHi,bHi)
// Every ds_read has a full MFMA cluster between issue and first use, so the
// compiler's per-use lgkmcnt(N) overlaps LDS drain with MFMA. 1 barrier/kt.
//
// Sync audit (the one vmcnt(0)+barrier at end-P2 of kt):
//  - guards P3's reads of buf[next]: all waves' 8 stages landed.  vmcnt(0)
//    has no counted-N edge cases (last kt: nothing outstanding, harmless).
//  - buf[cur] reads (issued P3(kt-1)/P0/P1) are all CONSUMED by P0/P1/P2
//    MFMAs (compiler use-waits) => returned before any wave passes the
//    barrier => kt+1's stages into buf[cur^1... wait next-next] never race.
//  - stages target buf[next] only; reads before the barrier target buf[cur].
//  - register WAR (aLo rewritten at P3 after last use at P1, etc.) is
//    per-wave in-order + compiler-tracked (plain C++ loads, rule #18 n/a).
// Seg boundary: loop runs seamlessly (seg0-kt31 stages+reads seg1-kt0);
// epilogue sits between P3(kt31,seg0) and P0(kt0,seg1); seg1-kt0's own
// vmcnt(0) drains the epilogue stores. No extra barriers needed.
// ---------------------------------------------------------------------------
#define BM 256
#define BN 256
#define BKB 128

#define MFMA __builtin_amdgcn_mfma_i32_16x16x64_i8

__global__ __launch_bounds__(512, 2) void gemm_i8_kernel(
    const int8_t* __restrict__ Xq, const int8_t* __restrict__ Wq,
    const float* __restrict__ xs, const float* __restrict__ ws,
    const float* __restrict__ bias, float* __restrict__ Y,
    int M, int N, int K)
{
    __shared__ __align__(16) int8_t smem[131072];

    const int tid  = threadIdx.x;
    const int lane = tid & 63;
    const int w    = tid >> 6;
    const int wrow = w >> 2, wcol = w & 3;

    // 256 blocks; XCD-aware: each XCD owns an 8x8 rect of the 32x16 tile grid.
    const int bid    = blockIdx.x;
    const int xcd    = bid & 7, idx = bid >> 3;        // idx in [0,32)
    const int bmBase = (xcd >> 1) * 8 + (idx >> 3);    // seg0 bm; seg1 = +4
    const int bn     = (xcd & 1) * 8 + (idx & 7);

    const int srcSwz = ((lane & 7) ^ (lane >> 3)) << 4;  // staging source swizzle
    const int chnk0  = ((lane >> 4) ^ (lane & 7)) << 4;  // frag read, k-slice 0
    const int chnk1  = chnk0 ^ 64;                       // k-slice 1
    const int aRB = ((wrow << 6) + (lane & 15)) << 7;    // A frag row-byte base
    const int bRB = ((wcol << 5) + (lane & 15)) << 7;    // B frag row-byte base

    auto STAGE = [&](const int8_t* gtile, int region, int rowStart) {
        const int8_t* src = gtile +
            (size_t)(rowStart + (w << 3) + (lane >> 3)) * K + srcSwz;
        __builtin_amdgcn_global_load_lds(
            (const __attribute__((address_space(1))) void*)src,
            (__attribute__((address_space(3))) void*)(smem + region + ((rowStart + (w << 3)) << 7)),
            16, 0, 0);
    };

    v4i acc[8][4] = {};
    v4i aLo[4][2], aHi[4][2], bLo[2][2], bHi[2][2];

    const int KT = K / BKB;   // 32
    const int8_t* bT0 = Wq + (size_t)bn * BN * K;   // same B panel both segs
    const int rowb = (lane >> 4) << 2;
    const int col  = lane & 15;

    // prologue: stage tile (seg0,kt0) into buf0; initial aLo/bLo reads
    {
        const int8_t* aT0 = Xq + (size_t)bmBase * BM * K;
        STAGE(aT0, 0,     0);   STAGE(aT0, 0,     64);
        STAGE(aT0, 0,     128); STAGE(aT0, 0,     192);
        STAGE(bT0, 32768, 0);   STAGE(bT0, 32768, 64);
        STAGE(bT0, 32768, 128); STAGE(bT0, 32768, 192);
        asm volatile("s_waitcnt vmcnt(0)" ::: "memory");
        __builtin_amdgcn_s_barrier();
#pragma unroll
        for (int i = 0; i < 4; ++i) {
            aLo[i][0] = *(const v4i*)(smem + aRB + i * 2048 + chnk0);
            aLo[i][1] = *(const v4i*)(smem + aRB + i * 2048 + chnk1);
        }
#pragma unroll
        for (int j = 0; j < 2; ++j) {
            bLo[j][0] = *(const v4i*)(smem + 32768 + bRB + j * 2048 + chnk0);
            bLo[j][1] = *(const v4i*)(smem + 32768 + bRB + j * 2048 + chnk1);
        }
    }

    for (int seg = 0; seg < 2; ++seg) {
        const int bm = bmBase + seg * 4;
        const int8_t* aT0 = Xq + (size_t)bm * BM * K;

        for (int kt = 0; kt < KT; ++kt) {
            const int Ab  = (kt & 1) * 65536;
            const int Bb  = Ab + 32768;
            const int nAb = ((kt & 1) ^ 1) * 65536;
            const int nBb = nAb + 32768;
            // next-tile pointers: next kt of this seg, or seg1's kt0
            const bool more = (kt + 1 < KT);
            const bool pf   = more || (seg == 0);
            const int8_t* aTn = more ? aT0 + (size_t)(kt + 1) * BKB
                                     : Xq + (size_t)(bmBase + 4) * BM * K;
            const int8_t* bTn = more ? bT0 + (size_t)(kt + 1) * BKB : bT0;

            // ---- P0: issue bHi reads; 4 stages; MFMA (lo,lo)
#pragma unroll
            for (int j = 0; j < 2; ++j) {
                bHi[j][0] = *(const v4i*)(smem + Bb + bRB + 16384 + j * 2048 + chnk0);
                bHi[j][1] = *(const v4i*)(smem + Bb + bRB + 16384 + j * 2048 + chnk1);
            }
            if (pf) { STAGE(aTn, nAb, 0);  STAGE(aTn, nAb, 64);
                      STAGE(bTn, nBb, 0);  STAGE(bTn, nBb, 64); }
            __builtin_amdgcn_s_setprio(1);
#pragma unroll
            for (int i = 0; i < 4; ++i)
#pragma unroll
                for (int j = 0; j < 2; ++j) {
                    acc[i][j] = MFMA(aLo[i][0], bLo[j][0], acc[i][j], 0, 0, 0);
                    acc[i][j] = MFMA(aLo[i][1], bLo[j][1], acc[i][j], 0, 0, 0);
                }
            __builtin_amdgcn_s_setprio(0);

            // ---- P1: issue aHi reads; 4 stages; MFMA (lo,hi)
#pragma unroll
            for (int i = 0; i < 4; ++i) {
                aHi[i][0] = *(const v4i*)(smem + Ab + aRB + 16384 + i * 2048 + chnk0);
                aHi[i][1] = *(const v4i*)(smem + Ab + aRB + 16384 + i * 2048 + chnk1);
            }
            if (pf) { STAGE(bTn, nBb, 128); STAGE(bTn, nBb, 192);
                      STAGE(aTn, nAb, 128); STAGE(aTn, nAb, 192); }
            __builtin_amdgcn_s_setprio(1);
#pragma unroll
            for (int i = 0; i < 4; ++i)
#pragma unroll
                for (int j = 0; j < 2; ++j) {
                    acc[i][2 + j] = MFMA(aLo[i][0], bHi[j][0], acc[i][2 + j], 0, 0, 0);
                    acc[i][2 + j] = MFMA(aLo[i][1], bHi[j][1], acc[i][2 + j], 0, 0, 0);
                }
            __builtin_amdgcn_s_setprio(0);

            // ---- P2: MFMA (hi,lo); then the per-kt sync point
            __builtin_amdgcn_s_setprio(1);
#pragma unroll
            for (int i = 0; i < 4; ++i)
#pragma unroll
                for (int j = 0; j < 2; ++j) {
                    acc[4 + i][j] = MFMA(aHi[i][0], bLo[j][0], acc[4 + i][j], 0, 0, 0);
                    acc[4 + i][j] = MFMA(aHi[i][1], bLo[j][1], acc[4 + i][j], 0, 0, 0);
                }
            __builtin_amdgcn_s_setprio(0);
            asm volatile("s_waitcnt vmcnt(0)" ::: "memory");  // all 8 stages landed
            __builtin_amdgcn_s_barrier();

            // ---- P3: issue aLo/bLo(next) reads from buf[next]; MFMA (hi,hi)
            if (pf) {
#pragma unroll
                for (int i = 0; i < 4; ++i) {
                    aLo[i][0] = *(const v4i*)(smem + nAb + aRB + i * 2048 + chnk0);
                    aLo[i][1] = *(const v4i*)(smem + nAb + aRB + i * 2048 + chnk1);
                }
#pragma unroll
                for (int j = 0; j < 2; ++j) {
                    bLo[j][0] = *(const v4i*)(smem + nBb + bRB + j * 2048 + chnk0);
                    bLo[j][1] = *(const v4i*)(smem + nBb + bRB + j * 2048 + chnk1);
                }
            }
            __builtin_amdgcn_s_setprio(1);
#pragma unroll
            for (int i = 0; i < 4; ++i)
#pragma unroll
                for (int j = 0; j < 2; ++j) {
                    acc[4 + i][2 + j] = MFMA(aHi[i][0], bHi[j][0], acc[4 + i][2 + j], 0, 0, 0);
                    acc[4 + i][2 + j] = MFMA(aHi[i][1], bHi[j][1], acc[4 + i][2 + j], 0, 0, 0);
                }
            __builtin_amdgcn_s_setprio(0);
        }

        // ----- epilogue: dequant + bias (layout col=lane&15, row=(lane>>4)*4+reg)
        {
            float wsv[4], bv[4];
#pragma unroll
            for (int j = 0; j < 4; ++j) {
                const int n = bn * BN + ((j >> 1) << 7) + (wcol << 5) + ((j & 1) << 4) + col;
                wsv[j] = ws[n];
                bv[j]  = bias[n];
            }
#pragma unroll
            for (int i = 0; i < 8; ++i) {
                const int mbase = bm * BM + ((i >> 2) << 7) + (wrow << 6) + ((i & 3) << 4) + rowb;
#pragma unroll
                for (int r = 0; r < 4; ++r) {
                    const int m = mbase + r;
                    const float xsm = xs[m];
                    float* yrow = Y + (size_t)m * N;
#pragma unroll
                    for (int j = 0; j < 4; ++j) {
                        const int n = bn * BN + ((j >> 1) << 7) + (wcol << 5) + ((j & 1) << 4) + col;
                        yrow[n] = (float)acc[i][j][r] * xsm * wsv[j] + bv[j];
                    }
                }
            }
        }

        if (seg == 0) {
#pragma unroll
            for (int i = 0; i < 8; ++i)
#pragma unroll
                for (int j = 0; j < 4; ++j)
                    acc[i][j] = (v4i){0, 0, 0, 0};
        }
    }
}

// ---------------------------------------------------------------------------
extern "C" void kernel_launch(void* const* d_in, const int* in_sizes, int n_in,
                              void* d_out, int out_size, void* d_ws, size_t ws_size,
                              hipStream_t stream) {
    const float* X    = (const float*)d_in[0];
    const float* W    = (const float*)d_in[1];
    const float* bias = (const float*)d_in[2];
    const float* ss   = (const float*)d_in[3];

    const int DIN  = in_sizes[3];              // 4096
    const int DOUT = in_sizes[2];              // 4096
    const int M    = in_sizes[0] / DIN;        // 8192

    int8_t* Xq = (int8_t*)d_ws;
    int8_t* Wq = Xq + (size_t)M * DIN;
    float*  xs = (float*)(Wq + (size_t)DOUT * DIN);
    float*  ws = xs + M;
    float*  Y  = (float*)d_out;

    quant_kernel<<<M + DOUT, 256, 0, stream>>>(X, W, ss, Xq, xs, Wq, ws, DIN, M);
    gemm_i8_kernel<<<(M / BM) * (DOUT / BN) / 2, 512, 0, stream>>>(Xq, Wq, xs, ws, bias, Y, M, DOUT, DIN);
}